// Round 2
// baseline (1750.818 us; speedup 1.0000x reference)
//
#include <hip/hip_runtime.h>

// Problem constants (from reference setup_inputs)
#define SZ0 1363968
#define SZ1 123904
#define SZ2 11264
#define SZ3 1024
#define NE0 1239040
#define NE1 112640
#define NE2 10240
#define DIN 128
#define DH  256
#define DOUT 64

// ---------------------------------------------------------------------------
// 1) Degree histogram for ALL THREE layers in one launch.
//    NE0, NE1, NE2 are all multiples of 256 -> each block maps to exactly one
//    segment, no divergence.
// ---------------------------------------------------------------------------
__global__ __launch_bounds__(256) void hist_all(
    const int* __restrict__ ed0, const int* __restrict__ ed1,
    const int* __restrict__ ed2, int* __restrict__ bk0,
    int* __restrict__ bk1, int* __restrict__ bk2)
{
    int e = blockIdx.x * 256 + threadIdx.x;
    if (e < NE0) {
        atomicAdd(&bk0[ed0[e]], 1);
    } else if (e < NE0 + NE1) {
        atomicAdd(&bk1[ed1[e - NE0]], 1);
    } else {
        atomicAdd(&bk2[ed2[e - NE0 - NE1]], 1);
    }
}

// ---------------------------------------------------------------------------
// 2) In-place exclusive scan; one 1024-thread block per counter array
//    (3 blocks). n is a multiple of 1024 for all layers.
// ---------------------------------------------------------------------------
__global__ __launch_bounds__(1024) void scan_all(
    int* __restrict__ a0, int n0, int* __restrict__ a1, int n1,
    int* __restrict__ a2, int n2)
{
    __shared__ int sums[1024];
    int* a; int n;
    if (blockIdx.x == 0)      { a = a0; n = n0; }
    else if (blockIdx.x == 1) { a = a1; n = n1; }
    else                      { a = a2; n = n2; }

    const int t = threadIdx.x;
    const int C = (n + 1023) >> 10;
    const int lo = t * C;
    const int hi = min(lo + C, n);
    int s = 0;
    for (int i = lo; i < hi; i++) s += a[i];
    sums[t] = s;
    __syncthreads();
    for (int off = 1; off < 1024; off <<= 1) {
        int v = (t >= off) ? sums[t - off] : 0;
        __syncthreads();
        sums[t] += v;
        __syncthreads();
    }
    int pre = (t == 0) ? 0 : sums[t - 1];
    for (int i = lo; i < hi; i++) { int v = a[i]; a[i] = pre; pre += v; }
}

// ---------------------------------------------------------------------------
// 3) Ticket-scatter for all three layers in one launch. After this,
//    bk[d] == end offset of bucket d.
// ---------------------------------------------------------------------------
__global__ __launch_bounds__(256) void bucket_all(
    const int* __restrict__ es0, const int* __restrict__ ed0,
    const int* __restrict__ es1, const int* __restrict__ ed1,
    const int* __restrict__ es2, const int* __restrict__ ed2,
    int* __restrict__ bk0, int* __restrict__ bk1, int* __restrict__ bk2,
    int* __restrict__ p0, int* __restrict__ p1, int* __restrict__ p2)
{
    int e = blockIdx.x * 256 + threadIdx.x;
    if (e < NE0) {
        int pos = atomicAdd(&bk0[ed0[e]], 1);
        p0[pos] = es0[e];
    } else if (e < NE0 + NE1) {
        int i = e - NE0;
        int pos = atomicAdd(&bk1[ed1[i]], 1);
        p1[pos] = es1[i];
    } else {
        int i = e - NE0 - NE1;
        int pos = atomicAdd(&bk2[ed2[i]], 1);
        p2[pos] = es2[i];
    }
}

// ---------------------------------------------------------------------------
// 4) Segmented gather-mean (layers 1-2 only now): one wave per dst row.
// ---------------------------------------------------------------------------
template <int D>
__global__ __launch_bounds__(256) void gather_mean(
    const float* __restrict__ X, const int* __restrict__ perm,
    const int* __restrict__ ends, float* __restrict__ out)
{
    constexpr int VEC = D / 64;
    const int wave = (blockIdx.x * 256 + threadIdx.x) >> 6;
    const int lane = threadIdx.x & 63;
    const int start = (wave == 0) ? 0 : ends[wave - 1];
    const int end = ends[wave];

    float acc0[VEC], acc1[VEC];
#pragma unroll
    for (int i = 0; i < VEC; i++) { acc0[i] = 0.0f; acc1[i] = 0.0f; }

    int e = start;
    for (; e + 2 <= end; e += 2) {
        int s0 = perm[e];
        int s1 = perm[e + 1];
        const float* p0 = X + (size_t)s0 * D + lane * VEC;
        const float* p1 = X + (size_t)s1 * D + lane * VEC;
        float4 v0 = *reinterpret_cast<const float4*>(p0);
        float4 v1 = *reinterpret_cast<const float4*>(p1);
        acc0[0] += v0.x; acc0[1] += v0.y; acc0[2] += v0.z; acc0[3] += v0.w;
        acc1[0] += v1.x; acc1[1] += v1.y; acc1[2] += v1.z; acc1[3] += v1.w;
    }
    if (e < end) {
        int s0 = perm[e];
        const float* p0 = X + (size_t)s0 * D + lane * VEC;
        float4 v0 = *reinterpret_cast<const float4*>(p0);
        acc0[0] += v0.x; acc0[1] += v0.y; acc0[2] += v0.z; acc0[3] += v0.w;
    }

    const float inv = 1.0f / (float)max(end - start, 1);
    float* o = out + (size_t)wave * D + lane * VEC;
    float4 v;
    v.x = (acc0[0] + acc1[0]) * inv;
    v.y = (acc0[1] + acc1[1]) * inv;
    v.z = (acc0[2] + acc1[2]) * inv;
    v.w = (acc0[3] + acc1[3]) * inv;
    *reinterpret_cast<float4*>(o) = v;
}

// ---------------------------------------------------------------------------
// Fused layer-0: gather-mean + SAGE GEMM in one kernel.
// Per block of BM=64 dst rows:
//   phase 1: gather ~640 random x rows (512B each), mean into LDS transposed
//            Am[k=128][m=64] (unroll-4 edge loop for MLP at 2 blocks/CU).
//   phase 2: full-N GEMM  h1[m] = relu(mean[m].Wl0 + x[m].Wr0 + bl0),
//            A1 read straight from LDS (no agg0 round-trip: saves 254 MB HBM),
//            A2 (x) staged into the dead Am[0..31] rows per 32-k tile.
// LDS: Am 128x68x4 = 34.8KB + Bs 32x260x4 = 33.3KB = 68KB -> 2 blocks/CU.
// ---------------------------------------------------------------------------
__global__ __launch_bounds__(256) void fused_sage0(
    const float* __restrict__ X, const int* __restrict__ perm,
    const int* __restrict__ ends, const float* __restrict__ B1,
    const float* __restrict__ B2, const float* __restrict__ bias,
    float* __restrict__ C)
{
    __shared__ float Am[DIN][68];    // [k][m] transposed; row stride 272B (16B mult)
    __shared__ float Bs[32][260];    // [k][n]

    const int tid = threadIdx.x;
    const int m0 = blockIdx.x * 64;
    const int wv = tid >> 6;         // 0..3
    const int lane = tid & 63;

    // ---- phase 1: gather-mean 64 rows (16 per wave) ----
    for (int r = wv; r < 64; r += 4) {
        const int row = m0 + r;
        const int start = (row == 0) ? 0 : ends[row - 1];
        const int end = ends[row];
        float a0 = 0, a1 = 0, b0 = 0, b1 = 0, c0 = 0, c1 = 0, d0 = 0, d1 = 0;
        int e = start;
        for (; e + 4 <= end; e += 4) {
            int s0 = perm[e], s1 = perm[e + 1], s2 = perm[e + 2], s3 = perm[e + 3];
            float2 v0 = *(const float2*)(X + (size_t)s0 * DIN + lane * 2);
            float2 v1 = *(const float2*)(X + (size_t)s1 * DIN + lane * 2);
            float2 v2 = *(const float2*)(X + (size_t)s2 * DIN + lane * 2);
            float2 v3 = *(const float2*)(X + (size_t)s3 * DIN + lane * 2);
            a0 += v0.x; a1 += v0.y; b0 += v1.x; b1 += v1.y;
            c0 += v2.x; c1 += v2.y; d0 += v3.x; d1 += v3.y;
        }
        for (; e < end; e++) {
            int s0 = perm[e];
            float2 v0 = *(const float2*)(X + (size_t)s0 * DIN + lane * 2);
            a0 += v0.x; a1 += v0.y;
        }
        const float inv = 1.0f / (float)max(end - start, 1);
        Am[lane * 2 + 0][r] = (a0 + b0 + c0 + d0) * inv;
        Am[lane * 2 + 1][r] = (a1 + b1 + c1 + d1) * inv;
    }
    __syncthreads();

    // ---- phase 2: GEMM, K = 128 (mean.Wl from LDS) + 128 (x.Wr) ----
    const int ty = tid >> 4;         // 0..15
    const int tx = tid & 15;         // 0..15

    float acc[4][16];
#pragma unroll
    for (int i = 0; i < 4; i++)
#pragma unroll
        for (int j = 0; j < 16; j++) acc[i][j] = 0.0f;

    for (int kt = 0; kt < 2 * DIN; kt += 32) {
        int abase;
        if (kt < DIN) {
            abase = kt;              // A1 = mean, already resident in Am
        } else {
            abase = 0;               // stage A2 = x rows into Am[0..31]
#pragma unroll
            for (int j = 0; j < 2; j++) {
                int id = tid * 2 + j;
                int m = id >> 3;
                int q = id & 7;
                float4 v = *reinterpret_cast<const float4*>(
                    X + (size_t)(m0 + m) * DIN + (kt - DIN) + q * 4);
                Am[q * 4 + 0][m] = v.x;
                Am[q * 4 + 1][m] = v.y;
                Am[q * 4 + 2][m] = v.z;
                Am[q * 4 + 3][m] = v.w;
            }
        }
        // stage B tile (32 x 256)
        const float* Bp = (kt < DIN) ? B1 : B2;
        const int kof = (kt < DIN) ? kt : kt - DIN;
#pragma unroll
        for (int j = 0; j < 8; j++) {
            int id = tid * 8 + j;
            int k = id >> 6;
            int c = id & 63;
            float4 v = *reinterpret_cast<const float4*>(
                Bp + (size_t)(kof + k) * DH + c * 4);
            *reinterpret_cast<float4*>(&Bs[k][c * 4]) = v;
        }
        __syncthreads();

#pragma unroll
        for (int kk = 0; kk < 32; kk++) {
            float4 av = *reinterpret_cast<const float4*>(&Am[abase + kk][ty * 4]);
            const float a[4] = {av.x, av.y, av.z, av.w};
#pragma unroll
            for (int g = 0; g < 4; g++) {
                float4 bv = *reinterpret_cast<const float4*>(&Bs[kk][g * 64 + tx * 4]);
                const float b[4] = {bv.x, bv.y, bv.z, bv.w};
#pragma unroll
                for (int i = 0; i < 4; i++)
#pragma unroll
                    for (int jj = 0; jj < 4; jj++)
                        acc[i][g * 4 + jj] += a[i] * b[jj];
            }
        }
        __syncthreads();
    }

    // epilogue: bias + relu, float4 stores (C row stride == 256)
#pragma unroll
    for (int i = 0; i < 4; i++) {
        const int row = m0 + ty * 4 + i;
#pragma unroll
        for (int g = 0; g < 4; g++) {
            const float4 bb = *reinterpret_cast<const float4*>(bias + g * 64 + tx * 4);
            float v0 = fmaxf(acc[i][g * 4 + 0] + bb.x, 0.0f);
            float v1 = fmaxf(acc[i][g * 4 + 1] + bb.y, 0.0f);
            float v2 = fmaxf(acc[i][g * 4 + 2] + bb.z, 0.0f);
            float v3 = fmaxf(acc[i][g * 4 + 3] + bb.w, 0.0f);
            float4 o; o.x = v0; o.y = v1; o.z = v2; o.w = v3;
            *reinterpret_cast<float4*>(C + (size_t)row * DH + g * 64 + tx * 4) = o;
        }
    }
}

// ---------------------------------------------------------------------------
// SAGE GEMM (layers 1-2): C[m][n] = act( A1[m].B1 + A2[m].B2 + bias )
// Full-N blocks -> A fetched exactly once from HBM.
// ---------------------------------------------------------------------------
template <int BM, int BN>
__global__ __launch_bounds__(256) void gemm_sage(
    const float* __restrict__ A1, const float* __restrict__ A2,
    const float* __restrict__ B1, const float* __restrict__ B2,
    const float* __restrict__ bias, float* __restrict__ C,
    int K1, int K2, int do_relu)
{
    constexpr int BK = 32;
    constexpr int ROWS = BM / 16;
    constexpr int G = BN / 64;
    constexpr int AF4 = (BM * 8) / 256;
    constexpr int BF4 = (BN * 8) / 256;

    __shared__ float As[BK][BM + 4];
    __shared__ float Bs[BK][BN + 4];

    const int tid = threadIdx.x;
    const int m0 = blockIdx.x * BM;
    const int ty = tid >> 4;
    const int tx = tid & 15;

    float acc[ROWS][G * 4];
#pragma unroll
    for (int i = 0; i < ROWS; i++)
#pragma unroll
        for (int j = 0; j < G * 4; j++) acc[i][j] = 0.0f;

    const int K = K1 + K2;
    for (int kt = 0; kt < K; kt += BK) {
        const float* Ap; const float* Bp; int lK, kof;
        if (kt < K1) { Ap = A1; Bp = B1; lK = K1; kof = kt; }
        else         { Ap = A2; Bp = B2; lK = K2; kof = kt - K1; }

#pragma unroll
        for (int j = 0; j < AF4; j++) {
            int id = tid * AF4 + j;
            int m = id >> 3;
            int q = id & 7;
            float4 v = *reinterpret_cast<const float4*>(
                Ap + (size_t)(m0 + m) * lK + kof + q * 4);
            As[q * 4 + 0][m] = v.x;
            As[q * 4 + 1][m] = v.y;
            As[q * 4 + 2][m] = v.z;
            As[q * 4 + 3][m] = v.w;
        }
#pragma unroll
        for (int j = 0; j < BF4; j++) {
            int id = tid * BF4 + j;
            int k = id / (BN / 4);
            int c = id % (BN / 4);
            float4 v = *reinterpret_cast<const float4*>(
                Bp + (size_t)(kof + k) * BN + c * 4);
            *reinterpret_cast<float4*>(&Bs[k][c * 4]) = v;
        }
        __syncthreads();

#pragma unroll
        for (int kk = 0; kk < BK; kk++) {
            float a[ROWS];
            if constexpr (ROWS == 4) {
                float4 av = *reinterpret_cast<const float4*>(&As[kk][ty * 4]);
                a[0] = av.x; a[1] = av.y; a[2] = av.z; a[3] = av.w;
            } else {
                float2 av = *reinterpret_cast<const float2*>(&As[kk][ty * 2]);
                a[0] = av.x; a[1] = av.y;
            }
#pragma unroll
            for (int g = 0; g < G; g++) {
                float4 bv = *reinterpret_cast<const float4*>(&Bs[kk][g * 64 + tx * 4]);
                const float b[4] = {bv.x, bv.y, bv.z, bv.w};
#pragma unroll
                for (int i = 0; i < ROWS; i++)
#pragma unroll
                    for (int jj = 0; jj < 4; jj++)
                        acc[i][g * 4 + jj] += a[i] * b[jj];
            }
        }
        __syncthreads();
    }

#pragma unroll
    for (int i = 0; i < ROWS; i++) {
        const int row = m0 + ty * ROWS + i;
#pragma unroll
        for (int g = 0; g < G; g++) {
            const float4 bb = *reinterpret_cast<const float4*>(bias + g * 64 + tx * 4);
            float v0 = acc[i][g * 4 + 0] + bb.x;
            float v1 = acc[i][g * 4 + 1] + bb.y;
            float v2 = acc[i][g * 4 + 2] + bb.z;
            float v3 = acc[i][g * 4 + 3] + bb.w;
            if (do_relu) {
                v0 = fmaxf(v0, 0.0f); v1 = fmaxf(v1, 0.0f);
                v2 = fmaxf(v2, 0.0f); v3 = fmaxf(v3, 0.0f);
            }
            float4 o; o.x = v0; o.y = v1; o.z = v2; o.w = v3;
            *reinterpret_cast<float4*>(C + (size_t)row * BN + g * 64 + tx * 4) = o;
        }
    }
}

extern "C" void kernel_launch(void* const* d_in, const int* in_sizes, int n_in,
                              void* d_out, int out_size, void* d_ws, size_t ws_size,
                              hipStream_t stream)
{
    const float* x   = (const float*)d_in[0];
    const float* Wl0 = (const float*)d_in[1];
    const float* bl0 = (const float*)d_in[2];
    const float* Wr0 = (const float*)d_in[3];
    const float* Wl1 = (const float*)d_in[4];
    const float* bl1 = (const float*)d_in[5];
    const float* Wr1 = (const float*)d_in[6];
    const float* Wl2 = (const float*)d_in[7];
    const float* bl2 = (const float*)d_in[8];
    const float* Wr2 = (const float*)d_in[9];
    const int* es0 = (const int*)d_in[10];
    const int* ed0 = (const int*)d_in[11];
    const int* es1 = (const int*)d_in[12];
    const int* ed1 = (const int*)d_in[13];
    const int* es2 = (const int*)d_in[14];
    const int* ed2 = (const int*)d_in[15];

    // Workspace layout (4B units). Only bk* needs zeroing. agg0 eliminated.
    int* bk0   = (int*)d_ws;                       // SZ1
    int* bk1   = bk0 + SZ1;                        // SZ2
    int* bk2   = bk1 + SZ2;                        // SZ3
    int* perm0 = bk2 + SZ3;                        // NE0
    int* perm1 = perm0 + NE0;                      // NE1
    int* perm2 = perm1 + NE1;                      // NE2
    float* agg1 = (float*)(perm2 + NE2);           // SZ2*DH
    float* agg2 = agg1 + (size_t)SZ2 * DH;         // SZ3*DH
    float* h1   = agg2 + (size_t)SZ3 * DH;         // SZ1*DH
    float* h2   = h1 + (size_t)SZ1 * DH;           // SZ2*DH

    hipMemsetAsync(bk0, 0, (size_t)(SZ1 + SZ2 + SZ3) * sizeof(int), stream);

    // ---- edge prep for all 3 layers: 3 launches ----
    constexpr int NET = NE0 + NE1 + NE2;
    hist_all<<<NET / 256, 256, 0, stream>>>(ed0, ed1, ed2, bk0, bk1, bk2);
    scan_all<<<3, 1024, 0, stream>>>(bk0, SZ1, bk1, SZ2, bk2, SZ3);
    bucket_all<<<NET / 256, 256, 0, stream>>>(es0, ed0, es1, ed1, es2, ed2,
                                              bk0, bk1, bk2, perm0, perm1, perm2);

    // ---- layer 0 fused: x(1363968x128) -> h1(123904x256), relu ----
    fused_sage0<<<SZ1 / 64, 256, 0, stream>>>(x, perm0, bk0, Wl0, Wr0, bl0, h1);

    // ---- layer 1: h1 -> h2(11264x256), no relu ----
    gather_mean<DH><<<SZ2 / 4, 256, 0, stream>>>(h1, perm1, bk1, agg1);
    gemm_sage<32, DH><<<SZ2 / 32, 256, 0, stream>>>(
        agg1, h1, Wl1, Wr1, bl1, h2, DH, DH, 0);

    // ---- layer 2: h2 -> out(1024x64), relu ----
    gather_mean<DH><<<SZ3 / 4, 256, 0, stream>>>(h2, perm2, bk2, agg2);
    gemm_sage<32, DOUT><<<SZ3 / 32, 256, 0, stream>>>(
        agg2, h2, Wl2, Wr2, bl2, (float*)d_out, DH, DH, 1);
}

// Round 3
// 1607.560 us; speedup vs baseline: 1.0891x; 1.0891x over previous
//
#include <hip/hip_runtime.h>

// Problem constants (from reference setup_inputs)
#define SZ0 1363968
#define SZ1 123904
#define SZ2 11264
#define SZ3 1024
#define NE0 1239040
#define NE1 112640
#define NE2 10240
#define DIN 128
#define DH  256
#define DOUT 64

// ---------------------------------------------------------------------------
// 1) Degree histogram for ALL THREE layers in one launch.
//    NE0, NE1, NE2 are all multiples of 256 -> each block maps to exactly one
//    segment, no divergence.
// ---------------------------------------------------------------------------
__global__ __launch_bounds__(256) void hist_all(
    const int* __restrict__ ed0, const int* __restrict__ ed1,
    const int* __restrict__ ed2, int* __restrict__ bk0,
    int* __restrict__ bk1, int* __restrict__ bk2)
{
    int e = blockIdx.x * 256 + threadIdx.x;
    if (e < NE0) {
        atomicAdd(&bk0[ed0[e]], 1);
    } else if (e < NE0 + NE1) {
        atomicAdd(&bk1[ed1[e - NE0]], 1);
    } else {
        atomicAdd(&bk2[ed2[e - NE0 - NE1]], 1);
    }
}

// ---------------------------------------------------------------------------
// 2) In-place exclusive scan; one 1024-thread block per counter array
//    (3 blocks). n is a multiple of 1024 for all layers.
// ---------------------------------------------------------------------------
__global__ __launch_bounds__(1024) void scan_all(
    int* __restrict__ a0, int n0, int* __restrict__ a1, int n1,
    int* __restrict__ a2, int n2)
{
    __shared__ int sums[1024];
    int* a; int n;
    if (blockIdx.x == 0)      { a = a0; n = n0; }
    else if (blockIdx.x == 1) { a = a1; n = n1; }
    else                      { a = a2; n = n2; }

    const int t = threadIdx.x;
    const int C = (n + 1023) >> 10;
    const int lo = t * C;
    const int hi = min(lo + C, n);
    int s = 0;
    for (int i = lo; i < hi; i++) s += a[i];
    sums[t] = s;
    __syncthreads();
    for (int off = 1; off < 1024; off <<= 1) {
        int v = (t >= off) ? sums[t - off] : 0;
        __syncthreads();
        sums[t] += v;
        __syncthreads();
    }
    int pre = (t == 0) ? 0 : sums[t - 1];
    for (int i = lo; i < hi; i++) { int v = a[i]; a[i] = pre; pre += v; }
}

// ---------------------------------------------------------------------------
// 3) Ticket-scatter for all three layers in one launch. After this,
//    bk[d] == end offset of bucket d.
// ---------------------------------------------------------------------------
__global__ __launch_bounds__(256) void bucket_all(
    const int* __restrict__ es0, const int* __restrict__ ed0,
    const int* __restrict__ es1, const int* __restrict__ ed1,
    const int* __restrict__ es2, const int* __restrict__ ed2,
    int* __restrict__ bk0, int* __restrict__ bk1, int* __restrict__ bk2,
    int* __restrict__ p0, int* __restrict__ p1, int* __restrict__ p2)
{
    int e = blockIdx.x * 256 + threadIdx.x;
    if (e < NE0) {
        int pos = atomicAdd(&bk0[ed0[e]], 1);
        p0[pos] = es0[e];
    } else if (e < NE0 + NE1) {
        int i = e - NE0;
        int pos = atomicAdd(&bk1[ed1[i]], 1);
        p1[pos] = es1[i];
    } else {
        int i = e - NE0 - NE1;
        int pos = atomicAdd(&bk2[ed2[i]], 1);
        p2[pos] = es2[i];
    }
}

// ---------------------------------------------------------------------------
// 4) Segmented gather-mean: one wave (64 lanes) per dst row, unroll-4 over
//    edges (4 independent row loads in flight/wave). No LDS, low VGPR ->
//    ~8 blocks/CU resident -> >=64KB in flight per CU >> the ~9KB needed to
//    cover HBM latency -> BW-bound.
//    Writes EVERY row (0 for empty buckets) -> no pre-zeroing of out needed.
// ---------------------------------------------------------------------------
template <int D>
__global__ __launch_bounds__(256) void gather_mean(
    const float* __restrict__ X, const int* __restrict__ perm,
    const int* __restrict__ ends, float* __restrict__ out)
{
    constexpr int VEC = D / 64;
    const int wave = (blockIdx.x * 256 + threadIdx.x) >> 6;
    const int lane = threadIdx.x & 63;
    const int start = (wave == 0) ? 0 : ends[wave - 1];
    const int end = ends[wave];

    float acc[4][VEC];
#pragma unroll
    for (int u = 0; u < 4; u++)
#pragma unroll
        for (int i = 0; i < VEC; i++) acc[u][i] = 0.0f;

    int e = start;
    for (; e + 4 <= end; e += 4) {
        int s0 = perm[e], s1 = perm[e + 1], s2 = perm[e + 2], s3 = perm[e + 3];
        const float* p0 = X + (size_t)s0 * D + lane * VEC;
        const float* p1 = X + (size_t)s1 * D + lane * VEC;
        const float* p2 = X + (size_t)s2 * D + lane * VEC;
        const float* p3 = X + (size_t)s3 * D + lane * VEC;
        if (VEC == 2) {
            float2 v0 = *reinterpret_cast<const float2*>(p0);
            float2 v1 = *reinterpret_cast<const float2*>(p1);
            float2 v2 = *reinterpret_cast<const float2*>(p2);
            float2 v3 = *reinterpret_cast<const float2*>(p3);
            acc[0][0] += v0.x; acc[0][1] += v0.y;
            acc[1][0] += v1.x; acc[1][1] += v1.y;
            acc[2][0] += v2.x; acc[2][1] += v2.y;
            acc[3][0] += v3.x; acc[3][1] += v3.y;
        } else {
            float4 v0 = *reinterpret_cast<const float4*>(p0);
            float4 v1 = *reinterpret_cast<const float4*>(p1);
            float4 v2 = *reinterpret_cast<const float4*>(p2);
            float4 v3 = *reinterpret_cast<const float4*>(p3);
            acc[0][0] += v0.x; acc[0][1] += v0.y; acc[0][2] += v0.z; acc[0][3] += v0.w;
            acc[1][0] += v1.x; acc[1][1] += v1.y; acc[1][2] += v1.z; acc[1][3] += v1.w;
            acc[2][0] += v2.x; acc[2][1] += v2.y; acc[2][2] += v2.z; acc[2][3] += v2.w;
            acc[3][0] += v3.x; acc[3][1] += v3.y; acc[3][2] += v3.z; acc[3][3] += v3.w;
        }
    }
    for (; e < end; e++) {
        int s0 = perm[e];
        const float* p0 = X + (size_t)s0 * D + lane * VEC;
        if (VEC == 2) {
            float2 v0 = *reinterpret_cast<const float2*>(p0);
            acc[0][0] += v0.x; acc[0][1] += v0.y;
        } else {
            float4 v0 = *reinterpret_cast<const float4*>(p0);
            acc[0][0] += v0.x; acc[0][1] += v0.y; acc[0][2] += v0.z; acc[0][3] += v0.w;
        }
    }

    const float inv = 1.0f / (float)max(end - start, 1);
    float* o = out + (size_t)wave * D + lane * VEC;
    if (VEC == 2) {
        float2 v;
        v.x = (acc[0][0] + acc[1][0] + acc[2][0] + acc[3][0]) * inv;
        v.y = (acc[0][1] + acc[1][1] + acc[2][1] + acc[3][1]) * inv;
        *reinterpret_cast<float2*>(o) = v;
    } else {
        float4 v;
        v.x = (acc[0][0] + acc[1][0] + acc[2][0] + acc[3][0]) * inv;
        v.y = (acc[0][1] + acc[1][1] + acc[2][1] + acc[3][1]) * inv;
        v.z = (acc[0][2] + acc[1][2] + acc[2][2] + acc[3][2]) * inv;
        v.w = (acc[0][3] + acc[1][3] + acc[2][3] + acc[3][3]) * inv;
        *reinterpret_cast<float4*>(o) = v;
    }
}

// ---------------------------------------------------------------------------
// Fused SAGE GEMM: C[m][n] = act( A1[m].B1[:,n] + A2[m].B2[:,n] + bias[n] )
// Full-N blocks: BN == N, grid = M/BM row blocks -> A fetched exactly ONCE
// from HBM (B is tiny and L2-resident). As stored transposed [k][m]; inner
// loop per thread-k: 1 A read + G float4 B reads feeding ROWS*G*4 FMAs.
// BM=64,BN=256: 64 FMA (128 VALU cyc) per 5 ds_read_b128 (~60 LDS cyc)
// -> VALU-bound. LDS 42.4KB -> 3 blocks/CU.
// ---------------------------------------------------------------------------
template <int BM, int BN>
__global__ __launch_bounds__(256) void gemm_sage(
    const float* __restrict__ A1, const float* __restrict__ A2,
    const float* __restrict__ B1, const float* __restrict__ B2,
    const float* __restrict__ bias, float* __restrict__ C,
    int K1, int K2, int do_relu)
{
    constexpr int BK = 32;
    constexpr int ROWS = BM / 16;
    constexpr int G = BN / 64;
    constexpr int AF4 = (BM * 8) / 256;
    constexpr int BF4 = (BN * 8) / 256;

    __shared__ float As[BK][BM + 4];
    __shared__ float Bs[BK][BN + 4];

    const int tid = threadIdx.x;
    const int m0 = blockIdx.x * BM;
    const int ty = tid >> 4;
    const int tx = tid & 15;

    float acc[ROWS][G * 4];
#pragma unroll
    for (int i = 0; i < ROWS; i++)
#pragma unroll
        for (int j = 0; j < G * 4; j++) acc[i][j] = 0.0f;

    const int K = K1 + K2;
    for (int kt = 0; kt < K; kt += BK) {
        const float* Ap; const float* Bp; int lK, kof;
        if (kt < K1) { Ap = A1; Bp = B1; lK = K1; kof = kt; }
        else         { Ap = A2; Bp = B2; lK = K2; kof = kt - K1; }

#pragma unroll
        for (int j = 0; j < AF4; j++) {
            int id = tid * AF4 + j;
            int m = id >> 3;
            int q = id & 7;
            float4 v = *reinterpret_cast<const float4*>(
                Ap + (size_t)(m0 + m) * lK + kof + q * 4);
            As[q * 4 + 0][m] = v.x;
            As[q * 4 + 1][m] = v.y;
            As[q * 4 + 2][m] = v.z;
            As[q * 4 + 3][m] = v.w;
        }
#pragma unroll
        for (int j = 0; j < BF4; j++) {
            int id = tid * BF4 + j;
            int k = id / (BN / 4);
            int c = id % (BN / 4);
            float4 v = *reinterpret_cast<const float4*>(
                Bp + (size_t)(kof + k) * BN + c * 4);
            *reinterpret_cast<float4*>(&Bs[k][c * 4]) = v;
        }
        __syncthreads();

#pragma unroll
        for (int kk = 0; kk < BK; kk++) {
            float a[ROWS];
            if constexpr (ROWS == 4) {
                float4 av = *reinterpret_cast<const float4*>(&As[kk][ty * 4]);
                a[0] = av.x; a[1] = av.y; a[2] = av.z; a[3] = av.w;
            } else {
                float2 av = *reinterpret_cast<const float2*>(&As[kk][ty * 2]);
                a[0] = av.x; a[1] = av.y;
            }
#pragma unroll
            for (int g = 0; g < G; g++) {
                float4 bv = *reinterpret_cast<const float4*>(&Bs[kk][g * 64 + tx * 4]);
                const float b[4] = {bv.x, bv.y, bv.z, bv.w};
#pragma unroll
                for (int i = 0; i < ROWS; i++)
#pragma unroll
                    for (int jj = 0; jj < 4; jj++)
                        acc[i][g * 4 + jj] += a[i] * b[jj];
            }
        }
        __syncthreads();
    }

#pragma unroll
    for (int i = 0; i < ROWS; i++) {
        const int row = m0 + ty * ROWS + i;
#pragma unroll
        for (int g = 0; g < G; g++) {
            const float4 bb = *reinterpret_cast<const float4*>(bias + g * 64 + tx * 4);
            float v0 = acc[i][g * 4 + 0] + bb.x;
            float v1 = acc[i][g * 4 + 1] + bb.y;
            float v2 = acc[i][g * 4 + 2] + bb.z;
            float v3 = acc[i][g * 4 + 3] + bb.w;
            if (do_relu) {
                v0 = fmaxf(v0, 0.0f); v1 = fmaxf(v1, 0.0f);
                v2 = fmaxf(v2, 0.0f); v3 = fmaxf(v3, 0.0f);
            }
            float4 o; o.x = v0; o.y = v1; o.z = v2; o.w = v3;
            *reinterpret_cast<float4*>(C + (size_t)row * BN + g * 64 + tx * 4) = o;
        }
    }
}

extern "C" void kernel_launch(void* const* d_in, const int* in_sizes, int n_in,
                              void* d_out, int out_size, void* d_ws, size_t ws_size,
                              hipStream_t stream)
{
    const float* x   = (const float*)d_in[0];
    const float* Wl0 = (const float*)d_in[1];
    const float* bl0 = (const float*)d_in[2];
    const float* Wr0 = (const float*)d_in[3];
    const float* Wl1 = (const float*)d_in[4];
    const float* bl1 = (const float*)d_in[5];
    const float* Wr1 = (const float*)d_in[6];
    const float* Wl2 = (const float*)d_in[7];
    const float* bl2 = (const float*)d_in[8];
    const float* Wr2 = (const float*)d_in[9];
    const int* es0 = (const int*)d_in[10];
    const int* ed0 = (const int*)d_in[11];
    const int* es1 = (const int*)d_in[12];
    const int* ed1 = (const int*)d_in[13];
    const int* es2 = (const int*)d_in[14];
    const int* ed2 = (const int*)d_in[15];

    // Workspace layout (4B units). Only bk* needs zeroing.
    int* bk0   = (int*)d_ws;                       // SZ1
    int* bk1   = bk0 + SZ1;                        // SZ2
    int* bk2   = bk1 + SZ2;                        // SZ3
    int* perm0 = bk2 + SZ3;                        // NE0
    int* perm1 = perm0 + NE0;                      // NE1
    int* perm2 = perm1 + NE1;                      // NE2
    float* agg0 = (float*)(perm2 + NE2);           // SZ1*DIN
    float* agg1 = agg0 + (size_t)SZ1 * DIN;        // SZ2*DH
    float* agg2 = agg1 + (size_t)SZ2 * DH;         // SZ3*DH
    float* h1   = agg2 + (size_t)SZ3 * DH;         // SZ1*DH
    float* h2   = agg0;  // alias: agg0 is dead after gemm0; SZ2*DH <= SZ1*DIN

    hipMemsetAsync(bk0, 0, (size_t)(SZ1 + SZ2 + SZ3) * sizeof(int), stream);

    // ---- edge prep for all 3 layers: 3 launches ----
    constexpr int NET = NE0 + NE1 + NE2;
    hist_all<<<NET / 256, 256, 0, stream>>>(ed0, ed1, ed2, bk0, bk1, bk2);
    scan_all<<<3, 1024, 0, stream>>>(bk0, SZ1, bk1, SZ2, bk2, SZ3);
    bucket_all<<<NET / 256, 256, 0, stream>>>(es0, ed0, es1, ed1, es2, ed2,
                                              bk0, bk1, bk2, perm0, perm1, perm2);

    // ---- layer 0: x(1363968x128) -> h1(123904x256), relu ----
    gather_mean<DIN><<<SZ1 / 4, 256, 0, stream>>>(x, perm0, bk0, agg0);
    gemm_sage<64, DH><<<SZ1 / 64, 256, 0, stream>>>(
        agg0, x, Wl0, Wr0, bl0, h1, DIN, DIN, 1);

    // ---- layer 1: h1 -> h2(11264x256), no relu ----
    gather_mean<DH><<<SZ2 / 4, 256, 0, stream>>>(h1, perm1, bk1, agg1);
    gemm_sage<32, DH><<<SZ2 / 32, 256, 0, stream>>>(
        agg1, h1, Wl1, Wr1, bl1, h2, DH, DH, 0);

    // ---- layer 2: h2 -> out(1024x64), relu ----
    gather_mean<DH><<<SZ3 / 4, 256, 0, stream>>>(h2, perm2, bk2, agg2);
    gemm_sage<32, DOUT><<<SZ3 / 32, 256, 0, stream>>>(
        agg2, h2, Wl2, Wr2, bl2, (float*)d_out, DH, DH, 1);
}

// Round 4
// 1533.067 us; speedup vs baseline: 1.1420x; 1.0486x over previous
//
#include <hip/hip_runtime.h>

// Problem constants (from reference setup_inputs)
#define SZ0 1363968
#define SZ1 123904
#define SZ2 11264
#define SZ3 1024
#define NE0 1239040
#define NE1 112640
#define NE2 10240
#define DIN 128
#define DH  256
#define DOUT 64

typedef __attribute__((ext_vector_type(8))) short bf16x8;
typedef __attribute__((ext_vector_type(4))) float f32x4;

__device__ __forceinline__ unsigned short f2bf(float f) {
    unsigned u = __float_as_uint(f);
    u += 0x7FFF + ((u >> 16) & 1);          // RNE
    return (unsigned short)(u >> 16);
}
__device__ __forceinline__ float bf2f(unsigned short h) {
    return __uint_as_float(((unsigned)h) << 16);
}

// ---------------------------------------------------------------------------
// 0) One-shot weight conversion for layer-0 GEMM: Wl0/Wr0 (128x256 fp32) ->
//    split-bf16 hi/lo in the exact LDS staging layout:
//    addr = (((h*4 + c)*4 + kbl)*256 + n)*8 + j   with k = c*32 + kbl*8 + j.
// ---------------------------------------------------------------------------
__global__ __launch_bounds__(256) void bconv0(
    const float* __restrict__ Wl, const float* __restrict__ Wr,
    unsigned short* __restrict__ Bh, unsigned short* __restrict__ Bl)
{
    int id = blockIdx.x * 256 + threadIdx.x;   // 65536 total
    int h = id >> 15;
    int k = (id >> 8) & 127;
    int n = id & 255;
    float w = (h ? Wr : Wl)[k * 256 + n];
    unsigned short hv = f2bf(w);
    unsigned short lv = f2bf(w - bf2f(hv));
    int c = k >> 5, kbl = (k >> 3) & 3, j = k & 7;
    int addr = (((h * 4 + c) * 4 + kbl) * 256 + n) * 8 + j;
    Bh[addr] = hv;
    Bl[addr] = lv;
}

// ---------------------------------------------------------------------------
// 1) Degree histogram for ALL THREE layers in one launch.
// ---------------------------------------------------------------------------
__global__ __launch_bounds__(256) void hist_all(
    const int* __restrict__ ed0, const int* __restrict__ ed1,
    const int* __restrict__ ed2, int* __restrict__ bk0,
    int* __restrict__ bk1, int* __restrict__ bk2)
{
    int e = blockIdx.x * 256 + threadIdx.x;
    if (e < NE0) {
        atomicAdd(&bk0[ed0[e]], 1);
    } else if (e < NE0 + NE1) {
        atomicAdd(&bk1[ed1[e - NE0]], 1);
    } else {
        atomicAdd(&bk2[ed2[e - NE0 - NE1]], 1);
    }
}

// ---------------------------------------------------------------------------
// 2) In-place exclusive scan; one 1024-thread block per counter array.
// ---------------------------------------------------------------------------
__global__ __launch_bounds__(1024) void scan_all(
    int* __restrict__ a0, int n0, int* __restrict__ a1, int n1,
    int* __restrict__ a2, int n2)
{
    __shared__ int sums[1024];
    int* a; int n;
    if (blockIdx.x == 0)      { a = a0; n = n0; }
    else if (blockIdx.x == 1) { a = a1; n = n1; }
    else                      { a = a2; n = n2; }

    const int t = threadIdx.x;
    const int C = (n + 1023) >> 10;
    const int lo = t * C;
    const int hi = min(lo + C, n);
    int s = 0;
    for (int i = lo; i < hi; i++) s += a[i];
    sums[t] = s;
    __syncthreads();
    for (int off = 1; off < 1024; off <<= 1) {
        int v = (t >= off) ? sums[t - off] : 0;
        __syncthreads();
        sums[t] += v;
        __syncthreads();
    }
    int pre = (t == 0) ? 0 : sums[t - 1];
    for (int i = lo; i < hi; i++) { int v = a[i]; a[i] = pre; pre += v; }
}

// ---------------------------------------------------------------------------
// 3) Ticket-scatter for all three layers in one launch.
// ---------------------------------------------------------------------------
__global__ __launch_bounds__(256) void bucket_all(
    const int* __restrict__ es0, const int* __restrict__ ed0,
    const int* __restrict__ es1, const int* __restrict__ ed1,
    const int* __restrict__ es2, const int* __restrict__ ed2,
    int* __restrict__ bk0, int* __restrict__ bk1, int* __restrict__ bk2,
    int* __restrict__ p0, int* __restrict__ p1, int* __restrict__ p2)
{
    int e = blockIdx.x * 256 + threadIdx.x;
    if (e < NE0) {
        int pos = atomicAdd(&bk0[ed0[e]], 1);
        p0[pos] = es0[e];
    } else if (e < NE0 + NE1) {
        int i = e - NE0;
        int pos = atomicAdd(&bk1[ed1[i]], 1);
        p1[pos] = es1[i];
    } else {
        int i = e - NE0 - NE1;
        int pos = atomicAdd(&bk2[ed2[i]], 1);
        p2[pos] = es2[i];
    }
}

// ---------------------------------------------------------------------------
// 4) Segmented gather-mean: one wave per dst row, unroll-4 (4 independent
//    row loads in flight/wave). No LDS -> full occupancy -> BW-bound.
// ---------------------------------------------------------------------------
template <int D>
__global__ __launch_bounds__(256) void gather_mean(
    const float* __restrict__ X, const int* __restrict__ perm,
    const int* __restrict__ ends, float* __restrict__ out)
{
    constexpr int VEC = D / 64;
    const int wave = (blockIdx.x * 256 + threadIdx.x) >> 6;
    const int lane = threadIdx.x & 63;
    const int start = (wave == 0) ? 0 : ends[wave - 1];
    const int end = ends[wave];

    float acc[4][VEC];
#pragma unroll
    for (int u = 0; u < 4; u++)
#pragma unroll
        for (int i = 0; i < VEC; i++) acc[u][i] = 0.0f;

    int e = start;
    for (; e + 4 <= end; e += 4) {
        int s0 = perm[e], s1 = perm[e + 1], s2 = perm[e + 2], s3 = perm[e + 3];
        const float* p0 = X + (size_t)s0 * D + lane * VEC;
        const float* p1 = X + (size_t)s1 * D + lane * VEC;
        const float* p2 = X + (size_t)s2 * D + lane * VEC;
        const float* p3 = X + (size_t)s3 * D + lane * VEC;
        if (VEC == 2) {
            float2 v0 = *reinterpret_cast<const float2*>(p0);
            float2 v1 = *reinterpret_cast<const float2*>(p1);
            float2 v2 = *reinterpret_cast<const float2*>(p2);
            float2 v3 = *reinterpret_cast<const float2*>(p3);
            acc[0][0] += v0.x; acc[0][1] += v0.y;
            acc[1][0] += v1.x; acc[1][1] += v1.y;
            acc[2][0] += v2.x; acc[2][1] += v2.y;
            acc[3][0] += v3.x; acc[3][1] += v3.y;
        } else {
            float4 v0 = *reinterpret_cast<const float4*>(p0);
            float4 v1 = *reinterpret_cast<const float4*>(p1);
            float4 v2 = *reinterpret_cast<const float4*>(p2);
            float4 v3 = *reinterpret_cast<const float4*>(p3);
            acc[0][0] += v0.x; acc[0][1] += v0.y; acc[0][2] += v0.z; acc[0][3] += v0.w;
            acc[1][0] += v1.x; acc[1][1] += v1.y; acc[1][2] += v1.z; acc[1][3] += v1.w;
            acc[2][0] += v2.x; acc[2][1] += v2.y; acc[2][2] += v2.z; acc[2][3] += v2.w;
            acc[3][0] += v3.x; acc[3][1] += v3.y; acc[3][2] += v3.z; acc[3][3] += v3.w;
        }
    }
    for (; e < end; e++) {
        int s0 = perm[e];
        const float* p0 = X + (size_t)s0 * D + lane * VEC;
        if (VEC == 2) {
            float2 v0 = *reinterpret_cast<const float2*>(p0);
            acc[0][0] += v0.x; acc[0][1] += v0.y;
        } else {
            float4 v0 = *reinterpret_cast<const float4*>(p0);
            acc[0][0] += v0.x; acc[0][1] += v0.y; acc[0][2] += v0.z; acc[0][3] += v0.w;
        }
    }

    const float inv = 1.0f / (float)max(end - start, 1);
    float* o = out + (size_t)wave * D + lane * VEC;
    if (VEC == 2) {
        float2 v;
        v.x = (acc[0][0] + acc[1][0] + acc[2][0] + acc[3][0]) * inv;
        v.y = (acc[0][1] + acc[1][1] + acc[2][1] + acc[3][1]) * inv;
        *reinterpret_cast<float2*>(o) = v;
    } else {
        float4 v;
        v.x = (acc[0][0] + acc[1][0] + acc[2][0] + acc[3][0]) * inv;
        v.y = (acc[0][1] + acc[1][1] + acc[2][1] + acc[3][1]) * inv;
        v.z = (acc[0][2] + acc[1][2] + acc[2][2] + acc[3][2]) * inv;
        v.w = (acc[0][3] + acc[1][3] + acc[2][3] + acc[3][3]) * inv;
        *reinterpret_cast<float4*>(o) = v;
    }
}

// ---------------------------------------------------------------------------
// 5) Layer-0 GEMM via split-bf16 MFMA.
//    C[m][n] = relu( A1[m]·Wl0 + A2[m]·Wr0 + bias ),  M=123904, K=128+128,
//    N=256.  a = a_hi + a_lo (bf16 each); products hh + hl + lh (lo*lo
//    dropped, rel err ~2^-17/elem).  BM=64, full-N, 4 waves; wave w owns
//    n in [w*64, w*64+64).  Per k-chunk(32) per wave: 16 ds_read_b128 ->
//    48 mfma_f32_16x16x32_bf16 (3:1).
//    Fragment maps (gfx950): A: row=l&15, k=8*(l>>4)+j ; B: col=l&15,
//    k=8*(l>>4)+j ; D: col=l&15, row=(l>>4)*4+r (m89-verified).
//    A LDS = row-major [64][128] bf16 with G4 XOR swizzle byte^=((row&7)<<4)
//    (conflict-free on both 8B staging writes and 16B frag reads).
//    B LDS = [kbl][n][8] (linear both ways).  LDS 64KB -> 2 blocks/CU.
// ---------------------------------------------------------------------------
__global__ __launch_bounds__(256) void gemm_sage0_mfma(
    const float* __restrict__ A1, const float* __restrict__ A2,
    const unsigned short* __restrict__ Bh_ws,
    const unsigned short* __restrict__ Bl_ws,
    const float* __restrict__ bias, float* __restrict__ C)
{
    __shared__ unsigned short Ah[64 * 128];     // 16 KB
    __shared__ unsigned short Al[64 * 128];     // 16 KB
    __shared__ unsigned short Bh[4 * 256 * 8];  // 16 KB
    __shared__ unsigned short Bl[4 * 256 * 8];  // 16 KB

    const int tid = threadIdx.x;
    const int m0 = blockIdx.x * 64;
    const int w = tid >> 6;          // wave 0..3
    const int lane = tid & 63;
    const int lg = lane >> 4;        // 0..3
    const int lr = lane & 15;

    f32x4 acc[4][4];
#pragma unroll
    for (int i = 0; i < 4; i++)
#pragma unroll
        for (int j = 0; j < 4; j++) acc[i][j] = (f32x4){0.f, 0.f, 0.f, 0.f};

    for (int h = 0; h < 2; h++) {
        const float* Asrc = h ? A2 : A1;
        for (int c = 0; c < 4; c++) {
            __syncthreads();   // previous chunk's MFMA reads done; safe to overwrite
            if (c == 0) {
                // stage + split-convert A half: 64 rows x 128 k fp32
#pragma unroll
                for (int j = 0; j < 8; j++) {
                    int id = j * 256 + tid;      // 0..2047, coalesced
                    int m = id >> 5;
                    int q = id & 31;
                    float4 v = *reinterpret_cast<const float4*>(
                        Asrc + (size_t)(m0 + m) * 128 + q * 4);
                    unsigned short h0 = f2bf(v.x), h1 = f2bf(v.y);
                    unsigned short h2 = f2bf(v.z), h3 = f2bf(v.w);
                    int off = (m * 256 + q * 8) ^ ((m & 7) << 4);
                    *reinterpret_cast<short4*>((char*)Ah + off) =
                        make_short4((short)h0, (short)h1, (short)h2, (short)h3);
                    short4 ls;
                    ls.x = (short)f2bf(v.x - bf2f(h0));
                    ls.y = (short)f2bf(v.y - bf2f(h1));
                    ls.z = (short)f2bf(v.z - bf2f(h2));
                    ls.w = (short)f2bf(v.w - bf2f(h3));
                    *reinterpret_cast<short4*>((char*)Al + off) = ls;
                }
            }
            // stage B chunk: pure linear 16 KB copies (pre-converted layout)
            {
                const float4* sh = reinterpret_cast<const float4*>(
                    Bh_ws + (size_t)(h * 4 + c) * 8192);
                const float4* sl = reinterpret_cast<const float4*>(
                    Bl_ws + (size_t)(h * 4 + c) * 8192);
#pragma unroll
                for (int j = 0; j < 4; j++) {
                    int id = j * 256 + tid;      // 0..1023
                    *reinterpret_cast<float4*>(&Bh[id * 8]) = sh[id];
                    *reinterpret_cast<float4*>(&Bl[id * 8]) = sl[id];
                }
            }
            __syncthreads();

            // compute: k = h*128 + c*32 + lg*8 + j
            bf16x8 ah[4], al[4];
#pragma unroll
            for (int mt = 0; mt < 4; mt++) {
                int row = mt * 16 + lr;
                int off = (row * 256 + (c * 4 + lg) * 16) ^ ((row & 7) << 4);
                ah[mt] = *reinterpret_cast<const bf16x8*>((const char*)Ah + off);
                al[mt] = *reinterpret_cast<const bf16x8*>((const char*)Al + off);
            }
#pragma unroll
            for (int nt = 0; nt < 4; nt++) {
                int bo = (lg * 256 + w * 64 + nt * 16 + lr) * 8;
                bf16x8 bh = *reinterpret_cast<const bf16x8*>(&Bh[bo]);
                bf16x8 bl = *reinterpret_cast<const bf16x8*>(&Bl[bo]);
#pragma unroll
                for (int mt = 0; mt < 4; mt++) {
                    acc[mt][nt] = __builtin_amdgcn_mfma_f32_16x16x32_bf16(
                        ah[mt], bh, acc[mt][nt], 0, 0, 0);
                    acc[mt][nt] = __builtin_amdgcn_mfma_f32_16x16x32_bf16(
                        ah[mt], bl, acc[mt][nt], 0, 0, 0);
                    acc[mt][nt] = __builtin_amdgcn_mfma_f32_16x16x32_bf16(
                        al[mt], bh, acc[mt][nt], 0, 0, 0);
                }
            }
        }
    }

    // epilogue: bias + relu; D map col=l&15, row=(l>>4)*4+r
#pragma unroll
    for (int nt = 0; nt < 4; nt++) {
        const int n = w * 64 + nt * 16 + lr;
        const float bv = bias[n];
#pragma unroll
        for (int mt = 0; mt < 4; mt++) {
#pragma unroll
            for (int r = 0; r < 4; r++) {
                const int row = m0 + mt * 16 + lg * 4 + r;
                float v = acc[mt][nt][r] + bv;
                v = fmaxf(v, 0.0f);
                C[(size_t)row * 256 + n] = v;
            }
        }
    }
}

// ---------------------------------------------------------------------------
// 6) SAGE GEMM fp32 (layers 1-2): C = act(A1·B1 + A2·B2 + bias), full-N.
// ---------------------------------------------------------------------------
template <int BM, int BN>
__global__ __launch_bounds__(256) void gemm_sage(
    const float* __restrict__ A1, const float* __restrict__ A2,
    const float* __restrict__ B1, const float* __restrict__ B2,
    const float* __restrict__ bias, float* __restrict__ C,
    int K1, int K2, int do_relu)
{
    constexpr int BK = 32;
    constexpr int ROWS = BM / 16;
    constexpr int G = BN / 64;
    constexpr int AF4 = (BM * 8) / 256;
    constexpr int BF4 = (BN * 8) / 256;

    __shared__ float As[BK][BM + 4];
    __shared__ float Bs[BK][BN + 4];

    const int tid = threadIdx.x;
    const int m0 = blockIdx.x * BM;
    const int ty = tid >> 4;
    const int tx = tid & 15;

    float acc[ROWS][G * 4];
#pragma unroll
    for (int i = 0; i < ROWS; i++)
#pragma unroll
        for (int j = 0; j < G * 4; j++) acc[i][j] = 0.0f;

    const int K = K1 + K2;
    for (int kt = 0; kt < K; kt += BK) {
        const float* Ap; const float* Bp; int lK, kof;
        if (kt < K1) { Ap = A1; Bp = B1; lK = K1; kof = kt; }
        else         { Ap = A2; Bp = B2; lK = K2; kof = kt - K1; }

#pragma unroll
        for (int j = 0; j < AF4; j++) {
            int id = tid * AF4 + j;
            int m = id >> 3;
            int q = id & 7;
            float4 v = *reinterpret_cast<const float4*>(
                Ap + (size_t)(m0 + m) * lK + kof + q * 4);
            As[q * 4 + 0][m] = v.x;
            As[q * 4 + 1][m] = v.y;
            As[q * 4 + 2][m] = v.z;
            As[q * 4 + 3][m] = v.w;
        }
#pragma unroll
        for (int j = 0; j < BF4; j++) {
            int id = tid * BF4 + j;
            int k = id / (BN / 4);
            int c = id % (BN / 4);
            float4 v = *reinterpret_cast<const float4*>(
                Bp + (size_t)(kof + k) * BN + c * 4);
            *reinterpret_cast<float4*>(&Bs[k][c * 4]) = v;
        }
        __syncthreads();

#pragma unroll
        for (int kk = 0; kk < BK; kk++) {
            float a[ROWS];
            if constexpr (ROWS == 4) {
                float4 av = *reinterpret_cast<const float4*>(&As[kk][ty * 4]);
                a[0] = av.x; a[1] = av.y; a[2] = av.z; a[3] = av.w;
            } else {
                float2 av = *reinterpret_cast<const float2*>(&As[kk][ty * 2]);
                a[0] = av.x; a[1] = av.y;
            }
#pragma unroll
            for (int g = 0; g < G; g++) {
                float4 bv = *reinterpret_cast<const float4*>(&Bs[kk][g * 64 + tx * 4]);
                const float b[4] = {bv.x, bv.y, bv.z, bv.w};
#pragma unroll
                for (int i = 0; i < ROWS; i++)
#pragma unroll
                    for (int jj = 0; jj < 4; jj++)
                        acc[i][g * 4 + jj] += a[i] * b[jj];
            }
        }
        __syncthreads();
    }

#pragma unroll
    for (int i = 0; i < ROWS; i++) {
        const int row = m0 + ty * ROWS + i;
#pragma unroll
        for (int g = 0; g < G; g++) {
            const float4 bb = *reinterpret_cast<const float4*>(bias + g * 64 + tx * 4);
            float v0 = acc[i][g * 4 + 0] + bb.x;
            float v1 = acc[i][g * 4 + 1] + bb.y;
            float v2 = acc[i][g * 4 + 2] + bb.z;
            float v3 = acc[i][g * 4 + 3] + bb.w;
            if (do_relu) {
                v0 = fmaxf(v0, 0.0f); v1 = fmaxf(v1, 0.0f);
                v2 = fmaxf(v2, 0.0f); v3 = fmaxf(v3, 0.0f);
            }
            float4 o; o.x = v0; o.y = v1; o.z = v2; o.w = v3;
            *reinterpret_cast<float4*>(C + (size_t)row * BN + g * 64 + tx * 4) = o;
        }
    }
}

extern "C" void kernel_launch(void* const* d_in, const int* in_sizes, int n_in,
                              void* d_out, int out_size, void* d_ws, size_t ws_size,
                              hipStream_t stream)
{
    const float* x   = (const float*)d_in[0];
    const float* Wl0 = (const float*)d_in[1];
    const float* bl0 = (const float*)d_in[2];
    const float* Wr0 = (const float*)d_in[3];
    const float* Wl1 = (const float*)d_in[4];
    const float* bl1 = (const float*)d_in[5];
    const float* Wr1 = (const float*)d_in[6];
    const float* Wl2 = (const float*)d_in[7];
    const float* bl2 = (const float*)d_in[8];
    const float* Wr2 = (const float*)d_in[9];
    const int* es0 = (const int*)d_in[10];
    const int* ed0 = (const int*)d_in[11];
    const int* es1 = (const int*)d_in[12];
    const int* ed1 = (const int*)d_in[13];
    const int* es2 = (const int*)d_in[14];
    const int* ed2 = (const int*)d_in[15];

    // Workspace layout (4B units). Only bk* needs zeroing.
    int* bk0   = (int*)d_ws;                       // SZ1
    int* bk1   = bk0 + SZ1;                        // SZ2
    int* bk2   = bk1 + SZ2;                        // SZ3
    int* perm0 = bk2 + SZ3;                        // NE0
    int* perm1 = perm0 + NE0;                      // NE1
    int* perm2 = perm1 + NE1;                      // NE2
    float* agg0 = (float*)(perm2 + NE2);           // SZ1*DIN
    float* agg1 = agg0 + (size_t)SZ1 * DIN;        // SZ2*DH
    float* agg2 = agg1 + (size_t)SZ2 * DH;         // SZ3*DH
    float* h1   = agg2 + (size_t)SZ3 * DH;         // SZ1*DH
    float* h2   = agg0;  // alias: agg0 dead after gemm0; SZ2*DH <= SZ1*DIN
    unsigned short* bwsh = (unsigned short*)(h1 + (size_t)SZ1 * DH);  // 65536
    unsigned short* bwsl = bwsh + 65536;                              // 65536

    hipMemsetAsync(bk0, 0, (size_t)(SZ1 + SZ2 + SZ3) * sizeof(int), stream);

    // ---- weight pre-convert (independent; overlaps nothing but is ~2 µs) ----
    bconv0<<<256, 256, 0, stream>>>(Wl0, Wr0, bwsh, bwsl);

    // ---- edge prep for all 3 layers: 3 launches ----
    constexpr int NET = NE0 + NE1 + NE2;
    hist_all<<<NET / 256, 256, 0, stream>>>(ed0, ed1, ed2, bk0, bk1, bk2);
    scan_all<<<3, 1024, 0, stream>>>(bk0, SZ1, bk1, SZ2, bk2, SZ3);
    bucket_all<<<NET / 256, 256, 0, stream>>>(es0, ed0, es1, ed1, es2, ed2,
                                              bk0, bk1, bk2, perm0, perm1, perm2);

    // ---- layer 0: x(1363968x128) -> h1(123904x256), relu (MFMA) ----
    gather_mean<DIN><<<SZ1 / 4, 256, 0, stream>>>(x, perm0, bk0, agg0);
    gemm_sage0_mfma<<<SZ1 / 64, 256, 0, stream>>>(agg0, x, bwsh, bwsl, bl0, h1);

    // ---- layer 1: h1 -> h2(11264x256), no relu ----
    gather_mean<DH><<<SZ2 / 4, 256, 0, stream>>>(h1, perm1, bk1, agg1);
    gemm_sage<32, DH><<<SZ2 / 32, 256, 0, stream>>>(
        agg1, h1, Wl1, Wr1, bl1, h2, DH, DH, 0);

    // ---- layer 2: h2 -> out(1024x64), relu ----
    gather_mean<DH><<<SZ3 / 4, 256, 0, stream>>>(h2, perm2, bk2, agg2);
    gemm_sage<32, DOUT><<<SZ3 / 32, 256, 0, stream>>>(
        agg2, h2, Wl2, Wr2, bl2, (float*)d_out, DH, DH, 1);
}

// Round 5
// 1466.957 us; speedup vs baseline: 1.1935x; 1.0451x over previous
//
#include <hip/hip_runtime.h>

// Problem constants (from reference setup_inputs)
#define SZ0 1363968
#define SZ1 123904
#define SZ2 11264
#define SZ3 1024
#define NE0 1239040
#define NE1 112640
#define NE2 10240
#define DIN 128
#define DH  256
#define DOUT 64

typedef __attribute__((ext_vector_type(8))) short bf16x8;
typedef __attribute__((ext_vector_type(4))) float f32x4;

__device__ __forceinline__ unsigned short f2bf(float f) {
    unsigned u = __float_as_uint(f);
    u += 0x7FFF + ((u >> 16) & 1);          // RNE
    return (unsigned short)(u >> 16);
}
__device__ __forceinline__ float bf2f(unsigned short h) {
    return __uint_as_float(((unsigned)h) << 16);
}

// ---------------------------------------------------------------------------
// 0) One-shot weight conversion for layer-0 AND layer-1 GEMMs -> split-bf16
//    hi/lo in the exact LDS staging layouts:
//    L0 (K=128): addr = (((h*4 + c)*4 + kbl)*256 + n)*8 + j, k = c*32+kbl*8+j
//    L1 (K=256): addr = (((h*8 + c)*4 + kbl)*256 + n)*8 + j, k = c*32+kbl*8+j
// ---------------------------------------------------------------------------
__global__ __launch_bounds__(256) void bconv_all(
    const float* __restrict__ Wl0, const float* __restrict__ Wr0,
    const float* __restrict__ Wl1, const float* __restrict__ Wr1,
    unsigned short* __restrict__ Bh0, unsigned short* __restrict__ Bl0,
    unsigned short* __restrict__ Bh1, unsigned short* __restrict__ Bl1)
{
    int id = blockIdx.x * 256 + threadIdx.x;   // 196608 total
    if (id < 65536) {
        int h = id >> 15;
        int k = (id >> 8) & 127;
        int n = id & 255;
        float w = (h ? Wr0 : Wl0)[k * 256 + n];
        unsigned short hv = f2bf(w);
        unsigned short lv = f2bf(w - bf2f(hv));
        int c = k >> 5, kbl = (k >> 3) & 3, j = k & 7;
        int addr = (((h * 4 + c) * 4 + kbl) * 256 + n) * 8 + j;
        Bh0[addr] = hv;
        Bl0[addr] = lv;
    } else {
        int t = id - 65536;
        int h = t >> 16;
        int k = (t >> 8) & 255;
        int n = t & 255;
        float w = (h ? Wr1 : Wl1)[k * 256 + n];
        unsigned short hv = f2bf(w);
        unsigned short lv = f2bf(w - bf2f(hv));
        int c = k >> 5, kbl = (k >> 3) & 3, j = k & 7;
        int addr = (((h * 8 + c) * 4 + kbl) * 256 + n) * 8 + j;
        Bh1[addr] = hv;
        Bl1[addr] = lv;
    }
}

// ---------------------------------------------------------------------------
// 1) Degree histogram for ALL THREE layers in one launch.
// ---------------------------------------------------------------------------
__global__ __launch_bounds__(256) void hist_all(
    const int* __restrict__ ed0, const int* __restrict__ ed1,
    const int* __restrict__ ed2, int* __restrict__ bk0,
    int* __restrict__ bk1, int* __restrict__ bk2)
{
    int e = blockIdx.x * 256 + threadIdx.x;
    if (e < NE0) {
        atomicAdd(&bk0[ed0[e]], 1);
    } else if (e < NE0 + NE1) {
        atomicAdd(&bk1[ed1[e - NE0]], 1);
    } else {
        atomicAdd(&bk2[ed2[e - NE0 - NE1]], 1);
    }
}

// ---------------------------------------------------------------------------
// 2) In-place exclusive scan; one 1024-thread block per counter array.
// ---------------------------------------------------------------------------
__global__ __launch_bounds__(1024) void scan_all(
    int* __restrict__ a0, int n0, int* __restrict__ a1, int n1,
    int* __restrict__ a2, int n2)
{
    __shared__ int sums[1024];
    int* a; int n;
    if (blockIdx.x == 0)      { a = a0; n = n0; }
    else if (blockIdx.x == 1) { a = a1; n = n1; }
    else                      { a = a2; n = n2; }

    const int t = threadIdx.x;
    const int C = (n + 1023) >> 10;
    const int lo = t * C;
    const int hi = min(lo + C, n);
    int s = 0;
    for (int i = lo; i < hi; i++) s += a[i];
    sums[t] = s;
    __syncthreads();
    for (int off = 1; off < 1024; off <<= 1) {
        int v = (t >= off) ? sums[t - off] : 0;
        __syncthreads();
        sums[t] += v;
        __syncthreads();
    }
    int pre = (t == 0) ? 0 : sums[t - 1];
    for (int i = lo; i < hi; i++) { int v = a[i]; a[i] = pre; pre += v; }
}

// ---------------------------------------------------------------------------
// 3) Ticket-scatter for all three layers in one launch.
// ---------------------------------------------------------------------------
__global__ __launch_bounds__(256) void bucket_all(
    const int* __restrict__ es0, const int* __restrict__ ed0,
    const int* __restrict__ es1, const int* __restrict__ ed1,
    const int* __restrict__ es2, const int* __restrict__ ed2,
    int* __restrict__ bk0, int* __restrict__ bk1, int* __restrict__ bk2,
    int* __restrict__ p0, int* __restrict__ p1, int* __restrict__ p2)
{
    int e = blockIdx.x * 256 + threadIdx.x;
    if (e < NE0) {
        int pos = atomicAdd(&bk0[ed0[e]], 1);
        p0[pos] = es0[e];
    } else if (e < NE0 + NE1) {
        int i = e - NE0;
        int pos = atomicAdd(&bk1[ed1[i]], 1);
        p1[pos] = es1[i];
    } else {
        int i = e - NE0 - NE1;
        int pos = atomicAdd(&bk2[ed2[i]], 1);
        p2[pos] = es2[i];
    }
}

// ---------------------------------------------------------------------------
// 4) Segmented gather-mean: one wave per dst row, unroll-4 (4 independent
//    row loads in flight/wave). No LDS -> full occupancy -> DRAM-bound
//    (random 512B/1KB granules; measured ~2 TB/s effective — granule limit).
// ---------------------------------------------------------------------------
template <int D>
__global__ __launch_bounds__(256) void gather_mean(
    const float* __restrict__ X, const int* __restrict__ perm,
    const int* __restrict__ ends, float* __restrict__ out)
{
    constexpr int VEC = D / 64;
    const int wave = (blockIdx.x * 256 + threadIdx.x) >> 6;
    const int lane = threadIdx.x & 63;
    const int start = (wave == 0) ? 0 : ends[wave - 1];
    const int end = ends[wave];

    float acc[4][VEC];
#pragma unroll
    for (int u = 0; u < 4; u++)
#pragma unroll
        for (int i = 0; i < VEC; i++) acc[u][i] = 0.0f;

    int e = start;
    for (; e + 4 <= end; e += 4) {
        int s0 = perm[e], s1 = perm[e + 1], s2 = perm[e + 2], s3 = perm[e + 3];
        const float* p0 = X + (size_t)s0 * D + lane * VEC;
        const float* p1 = X + (size_t)s1 * D + lane * VEC;
        const float* p2 = X + (size_t)s2 * D + lane * VEC;
        const float* p3 = X + (size_t)s3 * D + lane * VEC;
        if (VEC == 2) {
            float2 v0 = *reinterpret_cast<const float2*>(p0);
            float2 v1 = *reinterpret_cast<const float2*>(p1);
            float2 v2 = *reinterpret_cast<const float2*>(p2);
            float2 v3 = *reinterpret_cast<const float2*>(p3);
            acc[0][0] += v0.x; acc[0][1] += v0.y;
            acc[1][0] += v1.x; acc[1][1] += v1.y;
            acc[2][0] += v2.x; acc[2][1] += v2.y;
            acc[3][0] += v3.x; acc[3][1] += v3.y;
        } else {
            float4 v0 = *reinterpret_cast<const float4*>(p0);
            float4 v1 = *reinterpret_cast<const float4*>(p1);
            float4 v2 = *reinterpret_cast<const float4*>(p2);
            float4 v3 = *reinterpret_cast<const float4*>(p3);
            acc[0][0] += v0.x; acc[0][1] += v0.y; acc[0][2] += v0.z; acc[0][3] += v0.w;
            acc[1][0] += v1.x; acc[1][1] += v1.y; acc[1][2] += v1.z; acc[1][3] += v1.w;
            acc[2][0] += v2.x; acc[2][1] += v2.y; acc[2][2] += v2.z; acc[2][3] += v2.w;
            acc[3][0] += v3.x; acc[3][1] += v3.y; acc[3][2] += v3.z; acc[3][3] += v3.w;
        }
    }
    for (; e < end; e++) {
        int s0 = perm[e];
        const float* p0 = X + (size_t)s0 * D + lane * VEC;
        if (VEC == 2) {
            float2 v0 = *reinterpret_cast<const float2*>(p0);
            acc[0][0] += v0.x; acc[0][1] += v0.y;
        } else {
            float4 v0 = *reinterpret_cast<const float4*>(p0);
            acc[0][0] += v0.x; acc[0][1] += v0.y; acc[0][2] += v0.z; acc[0][3] += v0.w;
        }
    }

    const float inv = 1.0f / (float)max(end - start, 1);
    float* o = out + (size_t)wave * D + lane * VEC;
    if (VEC == 2) {
        float2 v;
        v.x = (acc[0][0] + acc[1][0] + acc[2][0] + acc[3][0]) * inv;
        v.y = (acc[0][1] + acc[1][1] + acc[2][1] + acc[3][1]) * inv;
        *reinterpret_cast<float2*>(o) = v;
    } else {
        float4 v;
        v.x = (acc[0][0] + acc[1][0] + acc[2][0] + acc[3][0]) * inv;
        v.y = (acc[0][1] + acc[1][1] + acc[2][1] + acc[3][1]) * inv;
        v.z = (acc[0][2] + acc[1][2] + acc[2][2] + acc[3][2]) * inv;
        v.w = (acc[0][3] + acc[1][3] + acc[2][3] + acc[3][3]) * inv;
        *reinterpret_cast<float4*>(o) = v;
    }
}

// ---------------------------------------------------------------------------
// 5) Layer-0 GEMM via split-bf16 MFMA (verified round 4).
//    C[m][n] = relu( A1[m]·Wl0 + A2[m]·Wr0 + bias ), K=128+128, N=256, BM=64.
//    a = hi + lo (bf16); products hh + hl + lh (lo·lo dropped).
//    A LDS row-major [64][128] bf16, XOR swizzle byte^=((row&7)<<4);
//    B LDS [kbl][n][8] linear. LDS 64KB -> 2 blocks/CU.
// ---------------------------------------------------------------------------
__global__ __launch_bounds__(256) void gemm_sage0_mfma(
    const float* __restrict__ A1, const float* __restrict__ A2,
    const unsigned short* __restrict__ Bh_ws,
    const unsigned short* __restrict__ Bl_ws,
    const float* __restrict__ bias, float* __restrict__ C)
{
    __shared__ unsigned short Ah[64 * 128];     // 16 KB
    __shared__ unsigned short Al[64 * 128];     // 16 KB
    __shared__ unsigned short Bh[4 * 256 * 8];  // 16 KB
    __shared__ unsigned short Bl[4 * 256 * 8];  // 16 KB

    const int tid = threadIdx.x;
    const int m0 = blockIdx.x * 64;
    const int w = tid >> 6;          // wave 0..3
    const int lane = tid & 63;
    const int lg = lane >> 4;        // 0..3
    const int lr = lane & 15;

    f32x4 acc[4][4];
#pragma unroll
    for (int i = 0; i < 4; i++)
#pragma unroll
        for (int j = 0; j < 4; j++) acc[i][j] = (f32x4){0.f, 0.f, 0.f, 0.f};

    for (int h = 0; h < 2; h++) {
        const float* Asrc = h ? A2 : A1;
        for (int c = 0; c < 4; c++) {
            __syncthreads();   // previous chunk's reads done; safe to overwrite
            if (c == 0) {
                // stage + split-convert A half: 64 rows x 128 k fp32
#pragma unroll
                for (int j = 0; j < 8; j++) {
                    int id = j * 256 + tid;      // 0..2047, coalesced
                    int m = id >> 5;
                    int q = id & 31;
                    float4 v = *reinterpret_cast<const float4*>(
                        Asrc + (size_t)(m0 + m) * 128 + q * 4);
                    unsigned short h0 = f2bf(v.x), h1 = f2bf(v.y);
                    unsigned short h2 = f2bf(v.z), h3 = f2bf(v.w);
                    int off = (m * 256 + q * 8) ^ ((m & 7) << 4);
                    *reinterpret_cast<short4*>((char*)Ah + off) =
                        make_short4((short)h0, (short)h1, (short)h2, (short)h3);
                    short4 ls;
                    ls.x = (short)f2bf(v.x - bf2f(h0));
                    ls.y = (short)f2bf(v.y - bf2f(h1));
                    ls.z = (short)f2bf(v.z - bf2f(h2));
                    ls.w = (short)f2bf(v.w - bf2f(h3));
                    *reinterpret_cast<short4*>((char*)Al + off) = ls;
                }
            }
            // stage B chunk: pure linear 16 KB copies (pre-converted layout)
            {
                const float4* sh = reinterpret_cast<const float4*>(
                    Bh_ws + (size_t)(h * 4 + c) * 8192);
                const float4* sl = reinterpret_cast<const float4*>(
                    Bl_ws + (size_t)(h * 4 + c) * 8192);
#pragma unroll
                for (int j = 0; j < 4; j++) {
                    int id = j * 256 + tid;      // 0..1023
                    *reinterpret_cast<float4*>(&Bh[id * 8]) = sh[id];
                    *reinterpret_cast<float4*>(&Bl[id * 8]) = sl[id];
                }
            }
            __syncthreads();

            // compute: k = h*128 + c*32 + lg*8 + j
            bf16x8 ah[4], al[4];
#pragma unroll
            for (int mt = 0; mt < 4; mt++) {
                int row = mt * 16 + lr;
                int off = (row * 256 + (c * 4 + lg) * 16) ^ ((row & 7) << 4);
                ah[mt] = *reinterpret_cast<const bf16x8*>((const char*)Ah + off);
                al[mt] = *reinterpret_cast<const bf16x8*>((const char*)Al + off);
            }
#pragma unroll
            for (int nt = 0; nt < 4; nt++) {
                int bo = (lg * 256 + w * 64 + nt * 16 + lr) * 8;
                bf16x8 bh = *reinterpret_cast<const bf16x8*>(&Bh[bo]);
                bf16x8 bl = *reinterpret_cast<const bf16x8*>(&Bl[bo]);
#pragma unroll
                for (int mt = 0; mt < 4; mt++) {
                    acc[mt][nt] = __builtin_amdgcn_mfma_f32_16x16x32_bf16(
                        ah[mt], bh, acc[mt][nt], 0, 0, 0);
                    acc[mt][nt] = __builtin_amdgcn_mfma_f32_16x16x32_bf16(
                        ah[mt], bl, acc[mt][nt], 0, 0, 0);
                    acc[mt][nt] = __builtin_amdgcn_mfma_f32_16x16x32_bf16(
                        al[mt], bh, acc[mt][nt], 0, 0, 0);
                }
            }
        }
    }

    // epilogue: bias + relu; D map col=l&15, row=(l>>4)*4+r
#pragma unroll
    for (int nt = 0; nt < 4; nt++) {
        const int n = w * 64 + nt * 16 + lr;
        const float bv = bias[n];
#pragma unroll
        for (int mt = 0; mt < 4; mt++) {
#pragma unroll
            for (int r = 0; r < 4; r++) {
                const int row = m0 + mt * 16 + lg * 4 + r;
                float v = acc[mt][nt][r] + bv;
                v = fmaxf(v, 0.0f);
                C[(size_t)row * 256 + n] = v;
            }
        }
    }
}

// ---------------------------------------------------------------------------
// 5b) Layer-1 GEMM via split-bf16 MFMA. Same scheme, BM=32, K=256+256.
//     h2[m][n] = A1[m]·Wl1 + A2[m]·Wr1 + bias (no relu).
//     A LDS [32][256] bf16 (row 512B) hi/lo, swizzle byte^=((row&7)<<4);
//     B per-32k chunk [kbl][n][8] linear. LDS 64KB -> 2 blocks/CU.
//     Per chunk per wave: 12 ds_read_b128 -> 24 MFMA.
// ---------------------------------------------------------------------------
__global__ __launch_bounds__(256) void gemm_sage1_mfma(
    const float* __restrict__ A1, const float* __restrict__ A2,
    const unsigned short* __restrict__ Bh_ws,
    const unsigned short* __restrict__ Bl_ws,
    const float* __restrict__ bias, float* __restrict__ C)
{
    __shared__ unsigned short Ah[32 * 256];     // 16 KB
    __shared__ unsigned short Al[32 * 256];     // 16 KB
    __shared__ unsigned short Bh[4 * 256 * 8];  // 16 KB
    __shared__ unsigned short Bl[4 * 256 * 8];  // 16 KB

    const int tid = threadIdx.x;
    const int m0 = blockIdx.x * 32;
    const int w = tid >> 6;          // wave 0..3
    const int lane = tid & 63;
    const int lg = lane >> 4;        // 0..3
    const int lr = lane & 15;

    f32x4 acc[2][4];
#pragma unroll
    for (int i = 0; i < 2; i++)
#pragma unroll
        for (int j = 0; j < 4; j++) acc[i][j] = (f32x4){0.f, 0.f, 0.f, 0.f};

    for (int h = 0; h < 2; h++) {
        const float* Asrc = h ? A2 : A1;
        __syncthreads();             // guards Ah/Al overwrite vs prev reads
        // stage + split-convert A half: 32 rows x 256 k fp32 (2048 float4)
#pragma unroll
        for (int j = 0; j < 8; j++) {
            int id = j * 256 + tid;
            int m = id >> 6;         // 0..31
            int q = id & 63;         // float4 index within 256-k row
            float4 v = *reinterpret_cast<const float4*>(
                Asrc + (size_t)(m0 + m) * 256 + q * 4);
            unsigned short h0 = f2bf(v.x), h1 = f2bf(v.y);
            unsigned short h2 = f2bf(v.z), h3 = f2bf(v.w);
            int off = (m * 512 + q * 8) ^ ((m & 7) << 4);
            *reinterpret_cast<short4*>((char*)Ah + off) =
                make_short4((short)h0, (short)h1, (short)h2, (short)h3);
            short4 ls;
            ls.x = (short)f2bf(v.x - bf2f(h0));
            ls.y = (short)f2bf(v.y - bf2f(h1));
            ls.z = (short)f2bf(v.z - bf2f(h2));
            ls.w = (short)f2bf(v.w - bf2f(h3));
            *reinterpret_cast<short4*>((char*)Al + off) = ls;
        }
        for (int c = 0; c < 8; c++) {
            if (c) __syncthreads();  // guards Bh/Bl overwrite vs prev reads
            const float4* sh = reinterpret_cast<const float4*>(
                Bh_ws + (size_t)(h * 8 + c) * 8192);
            const float4* sl = reinterpret_cast<const float4*>(
                Bl_ws + (size_t)(h * 8 + c) * 8192);
#pragma unroll
            for (int j = 0; j < 4; j++) {
                int id = j * 256 + tid;  // 0..1023
                *reinterpret_cast<float4*>(&Bh[id * 8]) = sh[id];
                *reinterpret_cast<float4*>(&Bl[id * 8]) = sl[id];
            }
            __syncthreads();

            // compute: k (within half) = c*32 + lg*8 + j
            bf16x8 ah[2], al[2];
#pragma unroll
            for (int mt = 0; mt < 2; mt++) {
                int row = mt * 16 + lr;
                int off = (row * 512 + (c * 4 + lg) * 16) ^ ((row & 7) << 4);
                ah[mt] = *reinterpret_cast<const bf16x8*>((const char*)Ah + off);
                al[mt] = *reinterpret_cast<const bf16x8*>((const char*)Al + off);
            }
#pragma unroll
            for (int nt = 0; nt < 4; nt++) {
                int bo = (lg * 256 + w * 64 + nt * 16 + lr) * 8;
                bf16x8 bh = *reinterpret_cast<const bf16x8*>(&Bh[bo]);
                bf16x8 bl = *reinterpret_cast<const bf16x8*>(&Bl[bo]);
#pragma unroll
                for (int mt = 0; mt < 2; mt++) {
                    acc[mt][nt] = __builtin_amdgcn_mfma_f32_16x16x32_bf16(
                        ah[mt], bh, acc[mt][nt], 0, 0, 0);
                    acc[mt][nt] = __builtin_amdgcn_mfma_f32_16x16x32_bf16(
                        ah[mt], bl, acc[mt][nt], 0, 0, 0);
                    acc[mt][nt] = __builtin_amdgcn_mfma_f32_16x16x32_bf16(
                        al[mt], bh, acc[mt][nt], 0, 0, 0);
                }
            }
        }
    }

    // epilogue: bias, NO relu
#pragma unroll
    for (int nt = 0; nt < 4; nt++) {
        const int n = w * 64 + nt * 16 + lr;
        const float bv = bias[n];
#pragma unroll
        for (int mt = 0; mt < 2; mt++) {
#pragma unroll
            for (int r = 0; r < 4; r++) {
                const int row = m0 + mt * 16 + lg * 4 + r;
                C[(size_t)row * 256 + n] = acc[mt][nt][r] + bv;
            }
        }
    }
}

// ---------------------------------------------------------------------------
// 6) SAGE GEMM fp32 (layer 2 only): C = act(A1·B1 + A2·B2 + bias), full-N.
// ---------------------------------------------------------------------------
template <int BM, int BN>
__global__ __launch_bounds__(256) void gemm_sage(
    const float* __restrict__ A1, const float* __restrict__ A2,
    const float* __restrict__ B1, const float* __restrict__ B2,
    const float* __restrict__ bias, float* __restrict__ C,
    int K1, int K2, int do_relu)
{
    constexpr int BK = 32;
    constexpr int ROWS = BM / 16;
    constexpr int G = BN / 64;
    constexpr int AF4 = (BM * 8) / 256;
    constexpr int BF4 = (BN * 8) / 256;

    __shared__ float As[BK][BM + 4];
    __shared__ float Bs[BK][BN + 4];

    const int tid = threadIdx.x;
    const int m0 = blockIdx.x * BM;
    const int ty = tid >> 4;
    const int tx = tid & 15;

    float acc[ROWS][G * 4];
#pragma unroll
    for (int i = 0; i < ROWS; i++)
#pragma unroll
        for (int j = 0; j < G * 4; j++) acc[i][j] = 0.0f;

    const int K = K1 + K2;
    for (int kt = 0; kt < K; kt += BK) {
        const float* Ap; const float* Bp; int lK, kof;
        if (kt < K1) { Ap = A1; Bp = B1; lK = K1; kof = kt; }
        else         { Ap = A2; Bp = B2; lK = K2; kof = kt - K1; }

#pragma unroll
        for (int j = 0; j < AF4; j++) {
            int id = tid * AF4 + j;
            int m = id >> 3;
            int q = id & 7;
            float4 v = *reinterpret_cast<const float4*>(
                Ap + (size_t)(m0 + m) * lK + kof + q * 4);
            As[q * 4 + 0][m] = v.x;
            As[q * 4 + 1][m] = v.y;
            As[q * 4 + 2][m] = v.z;
            As[q * 4 + 3][m] = v.w;
        }
#pragma unroll
        for (int j = 0; j < BF4; j++) {
            int id = tid * BF4 + j;
            int k = id / (BN / 4);
            int c = id % (BN / 4);
            float4 v = *reinterpret_cast<const float4*>(
                Bp + (size_t)(kof + k) * BN + c * 4);
            *reinterpret_cast<float4*>(&Bs[k][c * 4]) = v;
        }
        __syncthreads();

#pragma unroll
        for (int kk = 0; kk < BK; kk++) {
            float a[ROWS];
            if constexpr (ROWS == 4) {
                float4 av = *reinterpret_cast<const float4*>(&As[kk][ty * 4]);
                a[0] = av.x; a[1] = av.y; a[2] = av.z; a[3] = av.w;
            } else {
                float2 av = *reinterpret_cast<const float2*>(&As[kk][ty * 2]);
                a[0] = av.x; a[1] = av.y;
            }
#pragma unroll
            for (int g = 0; g < G; g++) {
                float4 bv = *reinterpret_cast<const float4*>(&Bs[kk][g * 64 + tx * 4]);
                const float b[4] = {bv.x, bv.y, bv.z, bv.w};
#pragma unroll
                for (int i = 0; i < ROWS; i++)
#pragma unroll
                    for (int jj = 0; jj < 4; jj++)
                        acc[i][g * 4 + jj] += a[i] * b[jj];
            }
        }
        __syncthreads();
    }

#pragma unroll
    for (int i = 0; i < ROWS; i++) {
        const int row = m0 + ty * ROWS + i;
#pragma unroll
        for (int g = 0; g < G; g++) {
            const float4 bb = *reinterpret_cast<const float4*>(bias + g * 64 + tx * 4);
            float v0 = acc[i][g * 4 + 0] + bb.x;
            float v1 = acc[i][g * 4 + 1] + bb.y;
            float v2 = acc[i][g * 4 + 2] + bb.z;
            float v3 = acc[i][g * 4 + 3] + bb.w;
            if (do_relu) {
                v0 = fmaxf(v0, 0.0f); v1 = fmaxf(v1, 0.0f);
                v2 = fmaxf(v2, 0.0f); v3 = fmaxf(v3, 0.0f);
            }
            float4 o; o.x = v0; o.y = v1; o.z = v2; o.w = v3;
            *reinterpret_cast<float4*>(C + (size_t)row * BN + g * 64 + tx * 4) = o;
        }
    }
}

extern "C" void kernel_launch(void* const* d_in, const int* in_sizes, int n_in,
                              void* d_out, int out_size, void* d_ws, size_t ws_size,
                              hipStream_t stream)
{
    const float* x   = (const float*)d_in[0];
    const float* Wl0 = (const float*)d_in[1];
    const float* bl0 = (const float*)d_in[2];
    const float* Wr0 = (const float*)d_in[3];
    const float* Wl1 = (const float*)d_in[4];
    const float* bl1 = (const float*)d_in[5];
    const float* Wr1 = (const float*)d_in[6];
    const float* Wl2 = (const float*)d_in[7];
    const float* bl2 = (const float*)d_in[8];
    const float* Wr2 = (const float*)d_in[9];
    const int* es0 = (const int*)d_in[10];
    const int* ed0 = (const int*)d_in[11];
    const int* es1 = (const int*)d_in[12];
    const int* ed1 = (const int*)d_in[13];
    const int* es2 = (const int*)d_in[14];
    const int* ed2 = (const int*)d_in[15];

    // Workspace layout (4B units). Only bk* needs zeroing.
    int* bk0   = (int*)d_ws;                       // SZ1
    int* bk1   = bk0 + SZ1;                        // SZ2
    int* bk2   = bk1 + SZ2;                        // SZ3
    int* perm0 = bk2 + SZ3;                        // NE0
    int* perm1 = perm0 + NE0;                      // NE1
    int* perm2 = perm1 + NE1;                      // NE2
    float* agg0 = (float*)(perm2 + NE2);           // SZ1*DIN
    float* agg1 = agg0 + (size_t)SZ1 * DIN;        // SZ2*DH
    float* agg2 = agg1 + (size_t)SZ2 * DH;         // SZ3*DH
    float* h1   = agg2 + (size_t)SZ3 * DH;         // SZ1*DH
    float* h2   = agg0;  // alias: agg0 dead after gemm0; SZ2*DH <= SZ1*DIN
    unsigned short* bwsh0 = (unsigned short*)(h1 + (size_t)SZ1 * DH); // 65536
    unsigned short* bwsl0 = bwsh0 + 65536;                           // 65536
    unsigned short* bwsh1 = bwsl0 + 65536;                           // 131072
    unsigned short* bwsl1 = bwsh1 + 131072;                          // 131072

    hipMemsetAsync(bk0, 0, (size_t)(SZ1 + SZ2 + SZ3) * sizeof(int), stream);

    // ---- weight pre-convert for layers 0+1 (one launch, ~3 µs) ----
    bconv_all<<<768, 256, 0, stream>>>(Wl0, Wr0, Wl1, Wr1,
                                       bwsh0, bwsl0, bwsh1, bwsl1);

    // ---- edge prep for all 3 layers: 3 launches ----
    constexpr int NET = NE0 + NE1 + NE2;
    hist_all<<<NET / 256, 256, 0, stream>>>(ed0, ed1, ed2, bk0, bk1, bk2);
    scan_all<<<3, 1024, 0, stream>>>(bk0, SZ1, bk1, SZ2, bk2, SZ3);
    bucket_all<<<NET / 256, 256, 0, stream>>>(es0, ed0, es1, ed1, es2, ed2,
                                              bk0, bk1, bk2, perm0, perm1, perm2);

    // ---- layer 0: x(1363968x128) -> h1(123904x256), relu (MFMA) ----
    gather_mean<DIN><<<SZ1 / 4, 256, 0, stream>>>(x, perm0, bk0, agg0);
    gemm_sage0_mfma<<<SZ1 / 64, 256, 0, stream>>>(agg0, x, bwsh0, bwsl0, bl0, h1);

    // ---- layer 1: h1 -> h2(11264x256), no relu (MFMA) ----
    gather_mean<DH><<<SZ2 / 4, 256, 0, stream>>>(h1, perm1, bk1, agg1);
    gemm_sage1_mfma<<<SZ2 / 32, 256, 0, stream>>>(agg1, h1, bwsh1, bwsl1, bl1, h2);

    // ---- layer 2: h2 -> out(1024x64), relu (fp32, tiny) ----
    gather_mean<DH><<<SZ3 / 4, 256, 0, stream>>>(h2, perm2, bk2, agg2);
    gemm_sage<32, DOUT><<<SZ3 / 32, 256, 0, stream>>>(
        agg2, h2, Wl2, Wr2, bl2, (float*)d_out, DH, DH, 1);
}